// Round 6
// baseline (7727.077 us; speedup 1.0000x reference)
//
#include <hip/hip_runtime.h>

// GNN: 3x (GraphConv -> BatchNorm -> ReLU) -> global_mean_pool -> Linear, fp32.
//
//  - CSR build once (hist -> parallel 3-stage scan -> reorder), reused 3x.
//  - aggregate: gather-side, atomic-free; applies previous layer's BN+ReLU per
//    gathered element AND materializes hT = t(h_raw) (own row, once) so the
//    GEMM is pure (enables global_load_lds DMA staging).
//  - gemm: 64x128 tile, K=256 concat, global_load_lds (16B) double-buffered
//    pipeline (no data VGPRs for staging -> no r3-style VGPR blowup),
//    col-stats fused in epilogue.
//  - Pool applies layer-3 (scale, shift), segmented over sorted batch.

constexpr int   NN   = 50000;
constexpr int   NE   = 800000;
constexpr int   DH   = 128;
constexpr int   NC   = 10;
constexpr int   NG   = 1024;
constexpr float EPSV = 1e-5f;
constexpr int   NB   = (NN + 255) / 256;   // 196 scan blocks

typedef const __attribute__((address_space(1))) void GVoid;
typedef __attribute__((address_space(3))) void LVoid;

// ------------------------------------------------------------- CSR build ---
__global__ __launch_bounds__(256) void hist_kernel(
    const int* __restrict__ dst, int* __restrict__ deg)
{
    int e = blockIdx.x * 256 + threadIdx.x;
    if (e < NE) atomicAdd(&deg[dst[e]], 1);
}

__global__ __launch_bounds__(256) void psum_kernel(
    const int* __restrict__ deg, int* __restrict__ bsum)
{
    int t = threadIdx.x;
    int i = blockIdx.x * 256 + t;
    int d = (i < NN) ? deg[i] : 0;
#pragma unroll
    for (int off = 32; off > 0; off >>= 1) d += __shfl_down(d, off, 64);
    __shared__ int w4[4];
    if ((t & 63) == 0) w4[t >> 6] = d;
    __syncthreads();
    if (t == 0) bsum[blockIdx.x] = w4[0] + w4[1] + w4[2] + w4[3];
}

__global__ __launch_bounds__(256) void scan_bsums_kernel(
    const int* __restrict__ bsum, int* __restrict__ bbase)
{
    __shared__ int tmp[256];
    int t = threadIdx.x;
    int v = (t < NB) ? bsum[t] : 0;
    tmp[t] = v;
    __syncthreads();
    for (int off = 1; off < 256; off <<= 1) {
        int u = (t >= off) ? tmp[t - off] : 0;
        __syncthreads();
        tmp[t] += u;
        __syncthreads();
    }
    if (t < NB) bbase[t] = tmp[t] - v;   // exclusive
}

__global__ __launch_bounds__(256) void offsets_kernel(
    const int* __restrict__ deg, const int* __restrict__ bbase,
    int* __restrict__ offsets, int* __restrict__ cursor)
{
    __shared__ int tmp[256];
    int t = threadIdx.x;
    int i = blockIdx.x * 256 + t;
    int d = (i < NN) ? deg[i] : 0;
    tmp[t] = d;
    __syncthreads();
    for (int off = 1; off < 256; off <<= 1) {
        int u = (t >= off) ? tmp[t - off] : 0;
        __syncthreads();
        tmp[t] += u;
        __syncthreads();
    }
    int incl = tmp[t];
    int base = bbase[blockIdx.x];
    if (i < NN) {
        int o = base + incl - d;
        offsets[i] = o;
        cursor[i]  = o;
        if (i == NN - 1) offsets[NN] = base + incl;
    }
}

__global__ __launch_bounds__(256) void reorder_kernel(
    const int* __restrict__ src, const int* __restrict__ dst,
    int* __restrict__ cursor, int* __restrict__ csr_src)
{
    int e = blockIdx.x * 256 + threadIdx.x;
    if (e < NE) {
        int pos = atomicAdd(&cursor[dst[e]], 1);
        csr_src[pos] = src[e];
    }
}

// -------------------------------------------------------------- aggregate ---
// 32 lanes per node, float4 per lane; 4-edge unroll. TRANSFORM applies prev
// layer's BN+ReLU per gathered element and writes hT[node] = t(x[node]).
template <bool TRANSFORM>
__global__ __launch_bounds__(256) void aggregate_kernel(
    const float* __restrict__ x, const int* __restrict__ offsets,
    const int* __restrict__ csr_src, const float* __restrict__ sc,
    const float* __restrict__ sh, float* __restrict__ agg,
    float* __restrict__ hT)
{
    int tid = blockIdx.x * 256 + threadIdx.x;
    int node = tid >> 5;
    if (node >= NN) return;
    int c4 = (tid & 31) << 2;

    float4 sc4, sh4;
    if (TRANSFORM) {
        sc4 = *reinterpret_cast<const float4*>(sc + c4);
        sh4 = *reinterpret_cast<const float4*>(sh + c4);
    }
    auto xf = [&](float4 v) -> float4 {
        if (TRANSFORM) {
            v.x = fmaxf(fmaf(v.x, sc4.x, sh4.x), 0.f);
            v.y = fmaxf(fmaf(v.y, sc4.y, sh4.y), 0.f);
            v.z = fmaxf(fmaf(v.z, sc4.z, sh4.z), 0.f);
            v.w = fmaxf(fmaf(v.w, sc4.w, sh4.w), 0.f);
        }
        return v;
    };

    if (TRANSFORM) {   // materialize transformed own row (once per row)
        float4 own = xf(*reinterpret_cast<const float4*>(x + (size_t)node * DH + c4));
        *reinterpret_cast<float4*>(hT + (size_t)node * DH + c4) = own;
    }

    int beg = offsets[node], end = offsets[node + 1];
    float4 acc = make_float4(0.f, 0.f, 0.f, 0.f);
    int e = beg;
    for (; e + 3 < end; e += 4) {
        int s0 = csr_src[e], s1 = csr_src[e + 1];
        int s2 = csr_src[e + 2], s3 = csr_src[e + 3];
        float4 v0 = xf(*reinterpret_cast<const float4*>(x + (size_t)s0 * DH + c4));
        float4 v1 = xf(*reinterpret_cast<const float4*>(x + (size_t)s1 * DH + c4));
        float4 v2 = xf(*reinterpret_cast<const float4*>(x + (size_t)s2 * DH + c4));
        float4 v3 = xf(*reinterpret_cast<const float4*>(x + (size_t)s3 * DH + c4));
        acc.x += (v0.x + v1.x) + (v2.x + v3.x);
        acc.y += (v0.y + v1.y) + (v2.y + v3.y);
        acc.z += (v0.z + v1.z) + (v2.z + v3.z);
        acc.w += (v0.w + v1.w) + (v2.w + v3.w);
    }
    for (; e < end; ++e) {
        int s0 = csr_src[e];
        float4 v0 = xf(*reinterpret_cast<const float4*>(x + (size_t)s0 * DH + c4));
        acc.x += v0.x; acc.y += v0.y; acc.z += v0.z; acc.w += v0.w;
    }
    *reinterpret_cast<float4*>(agg + (size_t)node * DH + c4) = acc;
}

// ------------------------------------------------------------------- gemm ---
// OUT = X @ Wr + A @ Wl + bias (pure, inputs pre-transformed).
// 64x128 tile, 256 threads, 8 rows x 4 cols/thread, K-step 32.
// Staging via global_load_lds (16B) into double-buffered LDS: no staging
// data registers, loads fly during compute, one barrier per K-step.
__global__ __launch_bounds__(256, 2) void gemm_fused_kernel(
    const float* __restrict__ X, const float* __restrict__ A,
    const float* __restrict__ Wr, const float* __restrict__ Wl,
    const float* __restrict__ bias, float* __restrict__ OUT,
    float* __restrict__ stats)
{
    __shared__ float sA[2][64 * 32];    // row-major [row][k]
    __shared__ float sW[2][32 * 128];   // row-major [k][col]

    const int tid  = threadIdx.x;
    const int col0 = (tid & 31) * 4;    // 32 distinct float4 cols (conflict-free)
    const int ty8  = (tid >> 5) * 8;    // 8 rows/thread (broadcast reads)
    const int row0 = blockIdx.x * 64;

    auto stage = [&](int t, int buf) {
        const float* inp = (t < 4) ? X : A;
        const float* Wp  = (t < 4) ? Wr : Wl;
        const int kb = (t * 32) & 127;
        // A tile: 64x32 fp32 = 512 float4 slots (2 issues)
#pragma unroll
        for (int is = 0; is < 2; ++is) {
            int f = is * 256 + tid;
            int grow = row0 + (f >> 3);
            grow = grow < NN ? grow : NN - 1;          // clamp: keep DMA in-bounds
            const float* g = inp + (size_t)grow * DH + kb + ((f & 7) << 2);
            __builtin_amdgcn_global_load_lds((GVoid*)g, (LVoid*)(&sA[buf][f * 4]), 16, 0, 0);
        }
        // W tile: 32x128 fp32 = 1024 float4 slots (4 issues)
#pragma unroll
        for (int is = 0; is < 4; ++is) {
            int f = is * 256 + tid;
            const float* g = Wp + (size_t)(kb + (f >> 5)) * DH + ((f & 31) << 2);
            __builtin_amdgcn_global_load_lds((GVoid*)g, (LVoid*)(&sW[buf][f * 4]), 16, 0, 0);
        }
    };

    float acc[8][4];
#pragma unroll
    for (int r = 0; r < 8; ++r)
#pragma unroll
        for (int j = 0; j < 4; ++j) acc[r][j] = 0.f;

    stage(0, 0);
    __syncthreads();   // compiler drains vmcnt(0) before barrier

#pragma unroll
    for (int t = 0; t < 8; ++t) {
        const int cur = t & 1;
        if (t < 7) stage(t + 1, cur ^ 1);

        const float* sa = &sA[cur][0];
        const float* sw = &sW[cur][0];
#pragma unroll
        for (int kq = 0; kq < 8; ++kq) {
            float4 a[8];
#pragma unroll
            for (int r = 0; r < 8; ++r)
                a[r] = *reinterpret_cast<const float4*>(sa + (ty8 + r) * 32 + kq * 4);
            float4 w0 = *reinterpret_cast<const float4*>(sw + (kq * 4 + 0) * 128 + col0);
            float4 w1 = *reinterpret_cast<const float4*>(sw + (kq * 4 + 1) * 128 + col0);
            float4 w2 = *reinterpret_cast<const float4*>(sw + (kq * 4 + 2) * 128 + col0);
            float4 w3 = *reinterpret_cast<const float4*>(sw + (kq * 4 + 3) * 128 + col0);
#pragma unroll
            for (int r = 0; r < 8; ++r) {
                acc[r][0] = fmaf(a[r].x, w0.x, acc[r][0]);
                acc[r][1] = fmaf(a[r].x, w0.y, acc[r][1]);
                acc[r][2] = fmaf(a[r].x, w0.z, acc[r][2]);
                acc[r][3] = fmaf(a[r].x, w0.w, acc[r][3]);
                acc[r][0] = fmaf(a[r].y, w1.x, acc[r][0]);
                acc[r][1] = fmaf(a[r].y, w1.y, acc[r][1]);
                acc[r][2] = fmaf(a[r].y, w1.z, acc[r][2]);
                acc[r][3] = fmaf(a[r].y, w1.w, acc[r][3]);
                acc[r][0] = fmaf(a[r].z, w2.x, acc[r][0]);
                acc[r][1] = fmaf(a[r].z, w2.y, acc[r][1]);
                acc[r][2] = fmaf(a[r].z, w2.z, acc[r][2]);
                acc[r][3] = fmaf(a[r].z, w2.w, acc[r][3]);
                acc[r][0] = fmaf(a[r].w, w3.x, acc[r][0]);
                acc[r][1] = fmaf(a[r].w, w3.y, acc[r][1]);
                acc[r][2] = fmaf(a[r].w, w3.z, acc[r][2]);
                acc[r][3] = fmaf(a[r].w, w3.w, acc[r][3]);
            }
        }
        __syncthreads();   // drains this iter's DMA (vmcnt 0) + protects buffers
    }

    // epilogue: bias, store, column stats
    float bv[4];
#pragma unroll
    for (int j = 0; j < 4; ++j) bv[j] = bias[col0 + j];

    float s_[4] = {0.f, 0.f, 0.f, 0.f}, q_[4] = {0.f, 0.f, 0.f, 0.f};

#pragma unroll
    for (int r = 0; r < 8; ++r) {
        int orow = row0 + ty8 + r;
        if (orow < NN) {
            float o[4];
#pragma unroll
            for (int j = 0; j < 4; ++j) {
                o[j] = acc[r][j] + bv[j];
                s_[j] += o[j];
                q_[j] += o[j] * o[j];
            }
            *reinterpret_cast<float4*>(OUT + (size_t)orow * DH + col0) =
                make_float4(o[0], o[1], o[2], o[3]);
        }
    }

    // reduce: lanes l and l+32 share columns
#pragma unroll
    for (int j = 0; j < 4; ++j) {
        s_[j] += __shfl_xor(s_[j], 32, 64);
        q_[j] += __shfl_xor(q_[j], 32, 64);
    }
    // reuse sA[0] as scratch (no one reads it after the last K-step barrier)
    float* ldsS = &sA[0][0];             // [4][128]
    float* ldsQ = ldsS + 512;            // [4][128]
    int lane = tid & 63, wave = tid >> 6;
    if (lane < 32) {
#pragma unroll
        for (int j = 0; j < 4; ++j) {
            ldsS[wave * DH + lane * 4 + j] = s_[j];
            ldsQ[wave * DH + lane * 4 + j] = q_[j];
        }
    }
    __syncthreads();
    if (tid < DH) {
        float s = ldsS[tid] + ldsS[DH + tid] + ldsS[2 * DH + tid] + ldsS[3 * DH + tid];
        float q = ldsQ[tid] + ldsQ[DH + tid] + ldsQ[2 * DH + tid] + ldsQ[3 * DH + tid];
        atomicAdd(&stats[tid], s);
        atomicAdd(&stats[DH + tid], q);
    }
}

// --------------------------------------------------------------- finalize ---
__global__ __launch_bounds__(128) void finalize_kernel(
    const float* __restrict__ stats, const float* __restrict__ gamma,
    const float* __restrict__ beta, float* __restrict__ sc,
    float* __restrict__ sh)
{
    int j = threadIdx.x;
    float mean = stats[j] * (1.f / NN);
    float var  = stats[DH + j] * (1.f / NN) - mean * mean;
    float s = rsqrtf(var + EPSV) * gamma[j];
    sc[j] = s;
    sh[j] = beta[j] - mean * s;
}

// ------------------------------------------------------------------- pool ---
__global__ __launch_bounds__(256) void ghist_kernel(
    const int* __restrict__ batch, int* __restrict__ gdeg)
{
    int n = blockIdx.x * 256 + threadIdx.x;
    if (n < NN) atomicAdd(&gdeg[batch[n]], 1);
}

__global__ __launch_bounds__(1024) void gscan_kernel(
    const int* __restrict__ gdeg, int* __restrict__ goff)
{
    __shared__ int part[1024];
    int t = threadIdx.x;
    part[t] = gdeg[t];
    __syncthreads();
    for (int off = 1; off < 1024; off <<= 1) {
        int v = (t >= off) ? part[t - off] : 0;
        __syncthreads();
        part[t] += v;
        __syncthreads();
    }
    goff[t + 1] = part[t];
    if (t == 0) goff[0] = 0;
}

__global__ __launch_bounds__(128) void pool_seg_kernel(
    const float* __restrict__ H, const int* __restrict__ goff,
    const float* __restrict__ sc, const float* __restrict__ sh,
    float* __restrict__ pooled)
{
    int g = blockIdx.x;
    int j = threadIdx.x;
    int beg = goff[g], end = goff[g + 1];
    float s = 0.f;
    for (int n = beg; n < end; ++n) s += H[(size_t)n * DH + j];
    float cnt = (float)(end - beg);
    float v = s * sc[j] + cnt * sh[j];
    pooled[(size_t)g * DH + j] = v / fmaxf(cnt, 1.f);
}

__global__ __launch_bounds__(64) void classify_kernel(
    const float* __restrict__ pooled, const float* __restrict__ wcls,
    const float* __restrict__ bcls, float* __restrict__ out)
{
    int g = blockIdx.x;
    int lane = threadIdx.x;
    float p0 = pooled[(size_t)g * DH + lane];
    float p1 = pooled[(size_t)g * DH + 64 + lane];
#pragma unroll
    for (int c = 0; c < NC; ++c) {
        float v = p0 * wcls[lane * NC + c] + p1 * wcls[(64 + lane) * NC + c];
#pragma unroll
        for (int off = 32; off > 0; off >>= 1) v += __shfl_down(v, off, 64);
        if (lane == 0) out[(size_t)g * NC + c] = v + bcls[c];
    }
}

// ----------------------------------------------------------------- launch ---
extern "C" void kernel_launch(void* const* d_in, const int* in_sizes, int n_in,
                              void* d_out, int out_size, void* d_ws, size_t ws_size,
                              hipStream_t stream)
{
    const float* x    = (const float*)d_in[0];
    const int*   ei   = (const int*)d_in[1];
    const int*   batch= (const int*)d_in[2];
    const float* wr1  = (const float*)d_in[3];
    const float* wl1  = (const float*)d_in[4];
    const float* b1   = (const float*)d_in[5];
    const float* wr2  = (const float*)d_in[6];
    const float* wl2  = (const float*)d_in[7];
    const float* b2   = (const float*)d_in[8];
    const float* wr3  = (const float*)d_in[9];
    const float* wl3  = (const float*)d_in[10];
    const float* b3   = (const float*)d_in[11];
    const float* g1   = (const float*)d_in[12];
    const float* be1  = (const float*)d_in[13];
    const float* g2   = (const float*)d_in[14];
    const float* be2  = (const float*)d_in[15];
    const float* g3   = (const float*)d_in[16];
    const float* be3  = (const float*)d_in[17];
    const float* wcls = (const float*)d_in[18];
    const float* bcls = (const float*)d_in[19];
    float* out = (float*)d_out;

    const int* srcp = ei;
    const int* dstp = ei + NE;

    char* ws = (char*)d_ws;
    const size_t featB = (size_t)NN * DH * sizeof(float);
    size_t off = 0;
    auto alloc = [&](size_t bytes) {
        void* p = ws + off;
        off += (bytes + 255) & ~(size_t)255;
        return p;
    };
    float* agg     = (float*)alloc(featB);
    float* hA      = (float*)alloc(featB);   // raw layer outputs
    float* hB      = (float*)alloc(featB);   // transformed inputs (hT)
    float* stats   = (float*)alloc(1024);
    float* pooled  = (float*)alloc((size_t)NG * DH * sizeof(float));
    int*   deg     = (int*)alloc(NN * sizeof(int));
    int*   offsets = (int*)alloc((NN + 1) * sizeof(int));
    int*   cursor  = (int*)alloc(NN * sizeof(int));
    int*   csr_src = (int*)alloc(NE * sizeof(int));
    int*   gdeg    = (int*)alloc(NG * sizeof(int));
    int*   goff    = (int*)alloc((NG + 1) * sizeof(int));
    int*   bsum    = (int*)alloc(NB * sizeof(int));
    int*   bbase   = (int*)alloc(NB * sizeof(int));
    float* sc1 = (float*)alloc(DH * 4); float* sh1 = (float*)alloc(DH * 4);
    float* sc2 = (float*)alloc(DH * 4); float* sh2 = (float*)alloc(DH * 4);
    float* sc3 = (float*)alloc(DH * 4); float* sh3 = (float*)alloc(DH * 4);

    const int edgeBlocks = (NE + 255) / 256;
    const int nodeBlocks = (NN + 255) / 256;     // == NB
    const int aggBlocks  = (NN * 32 + 255) / 256;
    const int gemmBlocks = (NN + 63) / 64;

    // ---- CSR build (once)
    hipMemsetAsync(deg, 0, NN * sizeof(int), stream);
    hist_kernel<<<edgeBlocks, 256, 0, stream>>>(dstp, deg);
    psum_kernel<<<NB, 256, 0, stream>>>(deg, bsum);
    scan_bsums_kernel<<<1, 256, 0, stream>>>(bsum, bbase);
    offsets_kernel<<<NB, 256, 0, stream>>>(deg, bbase, offsets, cursor);
    reorder_kernel<<<edgeBlocks, 256, 0, stream>>>(srcp, dstp, cursor, csr_src);

    // ---- graph ranges for pooling
    hipMemsetAsync(gdeg, 0, NG * sizeof(int), stream);
    ghist_kernel<<<nodeBlocks, 256, 0, stream>>>(batch, gdeg);
    gscan_kernel<<<1, 1024, 0, stream>>>(gdeg, goff);

    // ---- layer 1 (x already "transformed" input)
    aggregate_kernel<false><<<aggBlocks, 256, 0, stream>>>(x, offsets, csr_src, nullptr, nullptr, agg, nullptr);
    hipMemsetAsync(stats, 0, 1024, stream);
    gemm_fused_kernel<<<gemmBlocks, 256, 0, stream>>>(x, agg, wr1, wl1, b1, hA, stats);
    finalize_kernel<<<1, 128, 0, stream>>>(stats, g1, be1, sc1, sh1);

    // ---- layer 2 (raw1 = hA; t1 applied in aggregate; hT -> hB)
    aggregate_kernel<true><<<aggBlocks, 256, 0, stream>>>(hA, offsets, csr_src, sc1, sh1, agg, hB);
    hipMemsetAsync(stats, 0, 1024, stream);
    gemm_fused_kernel<<<gemmBlocks, 256, 0, stream>>>(hB, agg, wr2, wl2, b2, hA, stats);
    finalize_kernel<<<1, 128, 0, stream>>>(stats, g2, be2, sc2, sh2);

    // ---- layer 3 (raw2 = hA; t2 applied in aggregate; hT -> hB)
    aggregate_kernel<true><<<aggBlocks, 256, 0, stream>>>(hA, offsets, csr_src, sc2, sh2, agg, hB);
    hipMemsetAsync(stats, 0, 1024, stream);
    gemm_fused_kernel<<<gemmBlocks, 256, 0, stream>>>(hB, agg, wr3, wl3, b3, hA, stats);
    finalize_kernel<<<1, 128, 0, stream>>>(stats, g3, be3, sc3, sh3);

    // ---- pool (applies BN3, no ReLU) + classify
    pool_seg_kernel<<<NG, 128, 0, stream>>>(hA, goff, sc3, sh3, pooled);
    classify_kernel<<<NG, 64, 0, stream>>>(pooled, wcls, bcls, out);
}

// Round 7
// 504.142 us; speedup vs baseline: 15.3272x; 15.3272x over previous
//
#include <hip/hip_runtime.h>

// GNN: 3x (GraphConv -> BatchNorm -> ReLU) -> global_mean_pool -> Linear, fp32.
//
//  - CSR build once (hist -> parallel 3-stage scan -> reorder), reused 3x.
//  - Per layer: aggregate (gather-side, atomic-free, lazy BN+ReLU) ->
//    fused GEMM (concat-K 256, lazy BN on X path, col-stats in epilogue,
//    single-buffered LDS, k-major A tile, 32x128 tile / 4x4 micro-tile for
//    ~6 waves/SIMD occupancy) -> finalize.
//  - Pool applies layer-3 (scale, shift), segmented over sorted batch.
//
// History: r3 dbuf-in-registers blew VGPR 56->232 (reverted); r5
// global_load_lds with non-contiguous per-wave sources amplified HBM traffic
// 65x (reverted). Single-buffer + more waves is the stable configuration.

constexpr int   NN   = 50000;
constexpr int   NE   = 800000;
constexpr int   DH   = 128;
constexpr int   NC   = 10;
constexpr int   NG   = 1024;
constexpr float EPSV = 1e-5f;
constexpr int   NB   = (NN + 255) / 256;   // 196 scan blocks

// ------------------------------------------------------------- CSR build ---
__global__ __launch_bounds__(256) void hist_kernel(
    const int* __restrict__ dst, int* __restrict__ deg)
{
    int e = blockIdx.x * 256 + threadIdx.x;
    if (e < NE) atomicAdd(&deg[dst[e]], 1);
}

__global__ __launch_bounds__(256) void psum_kernel(
    const int* __restrict__ deg, int* __restrict__ bsum)
{
    int t = threadIdx.x;
    int i = blockIdx.x * 256 + t;
    int d = (i < NN) ? deg[i] : 0;
#pragma unroll
    for (int off = 32; off > 0; off >>= 1) d += __shfl_down(d, off, 64);
    __shared__ int w4[4];
    if ((t & 63) == 0) w4[t >> 6] = d;
    __syncthreads();
    if (t == 0) bsum[blockIdx.x] = w4[0] + w4[1] + w4[2] + w4[3];
}

__global__ __launch_bounds__(256) void scan_bsums_kernel(
    const int* __restrict__ bsum, int* __restrict__ bbase)
{
    __shared__ int tmp[256];
    int t = threadIdx.x;
    int v = (t < NB) ? bsum[t] : 0;
    tmp[t] = v;
    __syncthreads();
    for (int off = 1; off < 256; off <<= 1) {
        int u = (t >= off) ? tmp[t - off] : 0;
        __syncthreads();
        tmp[t] += u;
        __syncthreads();
    }
    if (t < NB) bbase[t] = tmp[t] - v;   // exclusive
}

__global__ __launch_bounds__(256) void offsets_kernel(
    const int* __restrict__ deg, const int* __restrict__ bbase,
    int* __restrict__ offsets, int* __restrict__ cursor)
{
    __shared__ int tmp[256];
    int t = threadIdx.x;
    int i = blockIdx.x * 256 + t;
    int d = (i < NN) ? deg[i] : 0;
    tmp[t] = d;
    __syncthreads();
    for (int off = 1; off < 256; off <<= 1) {
        int u = (t >= off) ? tmp[t - off] : 0;
        __syncthreads();
        tmp[t] += u;
        __syncthreads();
    }
    int incl = tmp[t];
    int base = bbase[blockIdx.x];
    if (i < NN) {
        int o = base + incl - d;
        offsets[i] = o;
        cursor[i]  = o;
        if (i == NN - 1) offsets[NN] = base + incl;
    }
}

__global__ __launch_bounds__(256) void reorder_kernel(
    const int* __restrict__ src, const int* __restrict__ dst,
    int* __restrict__ cursor, int* __restrict__ csr_src)
{
    int e = blockIdx.x * 256 + threadIdx.x;
    if (e < NE) {
        int pos = atomicAdd(&cursor[dst[e]], 1);
        csr_src[pos] = src[e];
    }
}

// -------------------------------------------------------------- aggregate ---
template <bool TRANSFORM>
__global__ __launch_bounds__(256) void aggregate_kernel(
    const float* __restrict__ x, const int* __restrict__ offsets,
    const int* __restrict__ csr_src, const float* __restrict__ sc,
    const float* __restrict__ sh, float* __restrict__ agg)
{
    int tid = blockIdx.x * 256 + threadIdx.x;
    int node = tid >> 5;
    if (node >= NN) return;
    int c4 = (tid & 31) << 2;

    float4 sc4, sh4;
    if (TRANSFORM) {
        sc4 = *reinterpret_cast<const float4*>(sc + c4);
        sh4 = *reinterpret_cast<const float4*>(sh + c4);
    }
    auto xf = [&](float4 v) -> float4 {
        if (TRANSFORM) {
            v.x = fmaxf(fmaf(v.x, sc4.x, sh4.x), 0.f);
            v.y = fmaxf(fmaf(v.y, sc4.y, sh4.y), 0.f);
            v.z = fmaxf(fmaf(v.z, sc4.z, sh4.z), 0.f);
            v.w = fmaxf(fmaf(v.w, sc4.w, sh4.w), 0.f);
        }
        return v;
    };

    int beg = offsets[node], end = offsets[node + 1];
    float4 acc = make_float4(0.f, 0.f, 0.f, 0.f);
    int e = beg;
    for (; e + 3 < end; e += 4) {
        int s0 = csr_src[e], s1 = csr_src[e + 1];
        int s2 = csr_src[e + 2], s3 = csr_src[e + 3];
        float4 v0 = xf(*reinterpret_cast<const float4*>(x + (size_t)s0 * DH + c4));
        float4 v1 = xf(*reinterpret_cast<const float4*>(x + (size_t)s1 * DH + c4));
        float4 v2 = xf(*reinterpret_cast<const float4*>(x + (size_t)s2 * DH + c4));
        float4 v3 = xf(*reinterpret_cast<const float4*>(x + (size_t)s3 * DH + c4));
        acc.x += (v0.x + v1.x) + (v2.x + v3.x);
        acc.y += (v0.y + v1.y) + (v2.y + v3.y);
        acc.z += (v0.z + v1.z) + (v2.z + v3.z);
        acc.w += (v0.w + v1.w) + (v2.w + v3.w);
    }
    for (; e < end; ++e) {
        int s0 = csr_src[e];
        float4 v0 = xf(*reinterpret_cast<const float4*>(x + (size_t)s0 * DH + c4));
        acc.x += v0.x; acc.y += v0.y; acc.z += v0.z; acc.w += v0.w;
    }
    *reinterpret_cast<float4*>(agg + (size_t)node * DH + c4) = acc;
}

// ------------------------------------------------------------------- gemm ---
// OUT = t(X) @ Wr + A @ Wl + bias, t = lazy BN+ReLU (TRANSFORM) or identity.
// 32x128 tile, 256 threads, 4 rows x 4 cols per thread, K-step 32,
// single-buffered LDS, k-major A tile. 1563 blocks -> ~6 waves/SIMD.
template <bool TRANSFORM>
__global__ __launch_bounds__(256) void gemm_fused_kernel(
    const float* __restrict__ X, const float* __restrict__ A,
    const float* __restrict__ Wr, const float* __restrict__ Wl,
    const float* __restrict__ bias, const float* __restrict__ scIn,
    const float* __restrict__ shIn, float* __restrict__ OUT,
    float* __restrict__ stats)
{
    __shared__ float sAT[32][36];       // k-major: [k][row], stride 36 (16B-aligned)
    __shared__ float sW[32][128];
    __shared__ float sScale[DH], sShift[DH];

    const int tid  = threadIdx.x;
    const int col0 = (tid & 31) * 4;      // 32 distinct float4 cols -> conflict-free
    const int ty4  = (tid >> 5) * 4;      // 4 rows per thread, broadcast reads
    const int row0 = blockIdx.x * 32;
    const int rA   = tid >> 3;            // staging row 0..31
    const int cA   = (tid & 7) * 4;       // staging k base 0..28
    const int wRow = tid >> 5;            // W staging k row base
    const int wCol = (tid & 31) * 4;

    if (TRANSFORM && tid < DH) {
        sScale[tid] = scIn[tid];
        sShift[tid] = shIn[tid];
    }
    __syncthreads();

    float acc[4][4];
#pragma unroll
    for (int r = 0; r < 4; ++r)
#pragma unroll
        for (int j = 0; j < 4; ++j) acc[r][j] = 0.f;

    const int grow = row0 + rA;
    for (int t = 0; t < 8; ++t) {
        const float* inp = (t < 4) ? X : A;
        const float* Wp  = (t < 4) ? Wr : Wl;
        const int kb = (t * 32) & 127;

        // stage A tile (k-major): one float4 per thread ---------------------
        float4 v0 = make_float4(0.f, 0.f, 0.f, 0.f);
        if (grow < NN) {
            v0 = *reinterpret_cast<const float4*>(inp + (size_t)grow * DH + kb + cA);
            if (TRANSFORM && t < 4) {
                int cb = kb + cA;
                v0.x = fmaxf(fmaf(v0.x, sScale[cb + 0], sShift[cb + 0]), 0.f);
                v0.y = fmaxf(fmaf(v0.y, sScale[cb + 1], sShift[cb + 1]), 0.f);
                v0.z = fmaxf(fmaf(v0.z, sScale[cb + 2], sShift[cb + 2]), 0.f);
                v0.w = fmaxf(fmaf(v0.w, sScale[cb + 3], sShift[cb + 3]), 0.f);
            }
        }
        const float* wb = Wp + (size_t)(kb + wRow) * DH + wCol;
        float4 w0 = *reinterpret_cast<const float4*>(wb);
        float4 w1 = *reinterpret_cast<const float4*>(wb + 8 * DH);
        float4 w2 = *reinterpret_cast<const float4*>(wb + 16 * DH);
        float4 w3 = *reinterpret_cast<const float4*>(wb + 24 * DH);

        sAT[cA + 0][rA] = v0.x; sAT[cA + 1][rA] = v0.y;
        sAT[cA + 2][rA] = v0.z; sAT[cA + 3][rA] = v0.w;
        *reinterpret_cast<float4*>(&sW[wRow][wCol])      = w0;
        *reinterpret_cast<float4*>(&sW[wRow + 8][wCol])  = w1;
        *reinterpret_cast<float4*>(&sW[wRow + 16][wCol]) = w2;
        *reinterpret_cast<float4*>(&sW[wRow + 24][wCol]) = w3;
        __syncthreads();

        // compute ----------------------------------------------------------
#pragma unroll
        for (int kk = 0; kk < 32; ++kk) {
            float4 a = *reinterpret_cast<const float4*>(&sAT[kk][ty4]);
            float4 w = *reinterpret_cast<const float4*>(&sW[kk][col0]);
            float av[4] = {a.x, a.y, a.z, a.w};
            float wv[4] = {w.x, w.y, w.z, w.w};
#pragma unroll
            for (int r = 0; r < 4; ++r)
#pragma unroll
                for (int j = 0; j < 4; ++j)
                    acc[r][j] = fmaf(av[r], wv[j], acc[r][j]);
        }
        __syncthreads();
    }

    // epilogue: bias, store, column stats
    float bv[4];
#pragma unroll
    for (int j = 0; j < 4; ++j) bv[j] = bias[col0 + j];

    float s_[4] = {0.f, 0.f, 0.f, 0.f}, q_[4] = {0.f, 0.f, 0.f, 0.f};

#pragma unroll
    for (int r = 0; r < 4; ++r) {
        int orow = row0 + ty4 + r;
        if (orow < NN) {
            float o[4];
#pragma unroll
            for (int j = 0; j < 4; ++j) {
                o[j] = acc[r][j] + bv[j];
                s_[j] += o[j];
                q_[j] += o[j] * o[j];
            }
            *reinterpret_cast<float4*>(OUT + (size_t)orow * DH + col0) =
                make_float4(o[0], o[1], o[2], o[3]);
        }
    }

    // reduce: lanes l and l+32 share columns
#pragma unroll
    for (int j = 0; j < 4; ++j) {
        s_[j] += __shfl_xor(s_[j], 32, 64);
        q_[j] += __shfl_xor(q_[j], 32, 64);
    }
    // reuse dead sAT buffer for the cross-wave reduction (32*36=1152 floats)
    float* ldsS = &sAT[0][0];            // [4][128]
    float* ldsQ = ldsS + 512;            // [4][128]
    int lane = tid & 63, wave = tid >> 6;
    if (lane < 32) {
#pragma unroll
        for (int j = 0; j < 4; ++j) {
            ldsS[wave * DH + lane * 4 + j] = s_[j];
            ldsQ[wave * DH + lane * 4 + j] = q_[j];
        }
    }
    __syncthreads();
    if (tid < DH) {
        float s = ldsS[tid] + ldsS[DH + tid] + ldsS[2 * DH + tid] + ldsS[3 * DH + tid];
        float q = ldsQ[tid] + ldsQ[DH + tid] + ldsQ[2 * DH + tid] + ldsQ[3 * DH + tid];
        atomicAdd(&stats[tid], s);
        atomicAdd(&stats[DH + tid], q);
    }
}

// --------------------------------------------------------------- finalize ---
__global__ __launch_bounds__(128) void finalize_kernel(
    const float* __restrict__ stats, const float* __restrict__ gamma,
    const float* __restrict__ beta, float* __restrict__ sc,
    float* __restrict__ sh)
{
    int j = threadIdx.x;
    float mean = stats[j] * (1.f / NN);
    float var  = stats[DH + j] * (1.f / NN) - mean * mean;
    float s = rsqrtf(var + EPSV) * gamma[j];
    sc[j] = s;
    sh[j] = beta[j] - mean * s;
}

// ------------------------------------------------------------------- pool ---
__global__ __launch_bounds__(256) void ghist_kernel(
    const int* __restrict__ batch, int* __restrict__ gdeg)
{
    int n = blockIdx.x * 256 + threadIdx.x;
    if (n < NN) atomicAdd(&gdeg[batch[n]], 1);
}

__global__ __launch_bounds__(1024) void gscan_kernel(
    const int* __restrict__ gdeg, int* __restrict__ goff)
{
    __shared__ int part[1024];
    int t = threadIdx.x;
    part[t] = gdeg[t];
    __syncthreads();
    for (int off = 1; off < 1024; off <<= 1) {
        int v = (t >= off) ? part[t - off] : 0;
        __syncthreads();
        part[t] += v;
        __syncthreads();
    }
    goff[t + 1] = part[t];
    if (t == 0) goff[0] = 0;
}

__global__ __launch_bounds__(128) void pool_seg_kernel(
    const float* __restrict__ H, const int* __restrict__ goff,
    const float* __restrict__ sc, const float* __restrict__ sh,
    float* __restrict__ pooled)
{
    int g = blockIdx.x;
    int j = threadIdx.x;
    int beg = goff[g], end = goff[g + 1];
    float s = 0.f;
    for (int n = beg; n < end; ++n) s += H[(size_t)n * DH + j];
    float cnt = (float)(end - beg);
    float v = s * sc[j] + cnt * sh[j];
    pooled[(size_t)g * DH + j] = v / fmaxf(cnt, 1.f);
}

__global__ __launch_bounds__(64) void classify_kernel(
    const float* __restrict__ pooled, const float* __restrict__ wcls,
    const float* __restrict__ bcls, float* __restrict__ out)
{
    int g = blockIdx.x;
    int lane = threadIdx.x;
    float p0 = pooled[(size_t)g * DH + lane];
    float p1 = pooled[(size_t)g * DH + 64 + lane];
#pragma unroll
    for (int c = 0; c < NC; ++c) {
        float v = p0 * wcls[lane * NC + c] + p1 * wcls[(64 + lane) * NC + c];
#pragma unroll
        for (int off = 32; off > 0; off >>= 1) v += __shfl_down(v, off, 64);
        if (lane == 0) out[(size_t)g * NC + c] = v + bcls[c];
    }
}

// ----------------------------------------------------------------- launch ---
extern "C" void kernel_launch(void* const* d_in, const int* in_sizes, int n_in,
                              void* d_out, int out_size, void* d_ws, size_t ws_size,
                              hipStream_t stream)
{
    const float* x    = (const float*)d_in[0];
    const int*   ei   = (const int*)d_in[1];
    const int*   batch= (const int*)d_in[2];
    const float* wr1  = (const float*)d_in[3];
    const float* wl1  = (const float*)d_in[4];
    const float* b1   = (const float*)d_in[5];
    const float* wr2  = (const float*)d_in[6];
    const float* wl2  = (const float*)d_in[7];
    const float* b2   = (const float*)d_in[8];
    const float* wr3  = (const float*)d_in[9];
    const float* wl3  = (const float*)d_in[10];
    const float* b3   = (const float*)d_in[11];
    const float* g1   = (const float*)d_in[12];
    const float* be1  = (const float*)d_in[13];
    const float* g2   = (const float*)d_in[14];
    const float* be2  = (const float*)d_in[15];
    const float* g3   = (const float*)d_in[16];
    const float* be3  = (const float*)d_in[17];
    const float* wcls = (const float*)d_in[18];
    const float* bcls = (const float*)d_in[19];
    float* out = (float*)d_out;

    const int* srcp = ei;
    const int* dstp = ei + NE;

    char* ws = (char*)d_ws;
    const size_t featB = (size_t)NN * DH * sizeof(float);
    size_t off = 0;
    auto alloc = [&](size_t bytes) {
        void* p = ws + off;
        off += (bytes + 255) & ~(size_t)255;
        return p;
    };
    float* agg     = (float*)alloc(featB);
    float* hA      = (float*)alloc(featB);
    float* hB      = (float*)alloc(featB);
    float* stats   = (float*)alloc(1024);
    float* pooled  = (float*)alloc((size_t)NG * DH * sizeof(float));
    int*   deg     = (int*)alloc(NN * sizeof(int));
    int*   offsets = (int*)alloc((NN + 1) * sizeof(int));
    int*   cursor  = (int*)alloc(NN * sizeof(int));
    int*   csr_src = (int*)alloc(NE * sizeof(int));
    int*   gdeg    = (int*)alloc(NG * sizeof(int));
    int*   goff    = (int*)alloc((NG + 1) * sizeof(int));
    int*   bsum    = (int*)alloc(NB * sizeof(int));
    int*   bbase   = (int*)alloc(NB * sizeof(int));
    float* sc1 = (float*)alloc(DH * 4); float* sh1 = (float*)alloc(DH * 4);
    float* sc2 = (float*)alloc(DH * 4); float* sh2 = (float*)alloc(DH * 4);
    float* sc3 = (float*)alloc(DH * 4); float* sh3 = (float*)alloc(DH * 4);

    const int edgeBlocks = (NE + 255) / 256;
    const int nodeBlocks = (NN + 255) / 256;     // == NB
    const int aggBlocks  = (NN * 32 + 255) / 256;
    const int gemmBlocks = (NN + 31) / 32;       // 1563

    // ---- CSR build (once)
    hipMemsetAsync(deg, 0, NN * sizeof(int), stream);
    hist_kernel<<<edgeBlocks, 256, 0, stream>>>(dstp, deg);
    psum_kernel<<<NB, 256, 0, stream>>>(deg, bsum);
    scan_bsums_kernel<<<1, 256, 0, stream>>>(bsum, bbase);
    offsets_kernel<<<NB, 256, 0, stream>>>(deg, bbase, offsets, cursor);
    reorder_kernel<<<edgeBlocks, 256, 0, stream>>>(srcp, dstp, cursor, csr_src);

    // ---- graph ranges for pooling
    hipMemsetAsync(gdeg, 0, NG * sizeof(int), stream);
    ghist_kernel<<<nodeBlocks, 256, 0, stream>>>(batch, gdeg);
    gscan_kernel<<<1, 1024, 0, stream>>>(gdeg, goff);

    // ---- layer 1
    aggregate_kernel<false><<<aggBlocks, 256, 0, stream>>>(x, offsets, csr_src, nullptr, nullptr, agg);
    hipMemsetAsync(stats, 0, 1024, stream);
    gemm_fused_kernel<false><<<gemmBlocks, 256, 0, stream>>>(x, agg, wr1, wl1, b1, nullptr, nullptr, hA, stats);
    finalize_kernel<<<1, 128, 0, stream>>>(stats, g1, be1, sc1, sh1);

    // ---- layer 2
    aggregate_kernel<true><<<aggBlocks, 256, 0, stream>>>(hA, offsets, csr_src, sc1, sh1, agg);
    hipMemsetAsync(stats, 0, 1024, stream);
    gemm_fused_kernel<true><<<gemmBlocks, 256, 0, stream>>>(hA, agg, wr2, wl2, b2, sc1, sh1, hB, stats);
    finalize_kernel<<<1, 128, 0, stream>>>(stats, g2, be2, sc2, sh2);

    // ---- layer 3
    aggregate_kernel<true><<<aggBlocks, 256, 0, stream>>>(hB, offsets, csr_src, sc2, sh2, agg);
    hipMemsetAsync(stats, 0, 1024, stream);
    gemm_fused_kernel<true><<<gemmBlocks, 256, 0, stream>>>(hB, agg, wr3, wl3, b3, sc2, sh2, hA, stats);
    finalize_kernel<<<1, 128, 0, stream>>>(stats, g3, be3, sc3, sh3);

    // ---- pool (applies BN3, no ReLU) + classify
    pool_seg_kernel<<<NG, 128, 0, stream>>>(hA, goff, sc3, sh3, pooled);
    classify_kernel<<<NG, 64, 0, stream>>>(pooled, wcls, bcls, out);
}

// Round 8
// 492.602 us; speedup vs baseline: 15.6862x; 1.0234x over previous
//
#include <hip/hip_runtime.h>

// GNN: 3x (GraphConv -> BatchNorm -> ReLU) -> global_mean_pool -> Linear, fp32.
//
//  - CSR build once (hist -> parallel 3-stage scan -> reorder), reused 3x.
//  - Per layer: aggregate (gather-side, atomic-free, lazy BN+ReLU) ->
//    fused GEMM (concat-K 256, lazy BN on X path, col-stats in epilogue,
//    single-buffered LDS, k-major A tile, 128x128 tile / 8x8 micro-tile:
//    1 B LDS per FMA -- r6 showed 4x4's 2 B/FMA saturates the CU LDS unit) ->
//    finalize.
//  - Pool applies layer-3 (scale, shift), segmented over sorted batch.
//
// History: r3 dbuf-in-registers blew VGPR 56->232 (reverted); r5
// global_load_lds with non-contiguous per-wave sources amplified HBM traffic
// 65x (reverted); r6 higher occupancy didn't help (LDS-BW-bound, not TLP).

constexpr int   NN   = 50000;
constexpr int   NE   = 800000;
constexpr int   DH   = 128;
constexpr int   NC   = 10;
constexpr int   NG   = 1024;
constexpr float EPSV = 1e-5f;
constexpr int   NB   = (NN + 255) / 256;   // 196 scan blocks

// ------------------------------------------------------------- CSR build ---
__global__ __launch_bounds__(256) void hist_kernel(
    const int* __restrict__ dst, int* __restrict__ deg)
{
    int e = blockIdx.x * 256 + threadIdx.x;
    if (e < NE) atomicAdd(&deg[dst[e]], 1);
}

__global__ __launch_bounds__(256) void psum_kernel(
    const int* __restrict__ deg, int* __restrict__ bsum)
{
    int t = threadIdx.x;
    int i = blockIdx.x * 256 + t;
    int d = (i < NN) ? deg[i] : 0;
#pragma unroll
    for (int off = 32; off > 0; off >>= 1) d += __shfl_down(d, off, 64);
    __shared__ int w4[4];
    if ((t & 63) == 0) w4[t >> 6] = d;
    __syncthreads();
    if (t == 0) bsum[blockIdx.x] = w4[0] + w4[1] + w4[2] + w4[3];
}

__global__ __launch_bounds__(256) void scan_bsums_kernel(
    const int* __restrict__ bsum, int* __restrict__ bbase)
{
    __shared__ int tmp[256];
    int t = threadIdx.x;
    int v = (t < NB) ? bsum[t] : 0;
    tmp[t] = v;
    __syncthreads();
    for (int off = 1; off < 256; off <<= 1) {
        int u = (t >= off) ? tmp[t - off] : 0;
        __syncthreads();
        tmp[t] += u;
        __syncthreads();
    }
    if (t < NB) bbase[t] = tmp[t] - v;   // exclusive
}

__global__ __launch_bounds__(256) void offsets_kernel(
    const int* __restrict__ deg, const int* __restrict__ bbase,
    int* __restrict__ offsets, int* __restrict__ cursor)
{
    __shared__ int tmp[256];
    int t = threadIdx.x;
    int i = blockIdx.x * 256 + t;
    int d = (i < NN) ? deg[i] : 0;
    tmp[t] = d;
    __syncthreads();
    for (int off = 1; off < 256; off <<= 1) {
        int u = (t >= off) ? tmp[t - off] : 0;
        __syncthreads();
        tmp[t] += u;
        __syncthreads();
    }
    int incl = tmp[t];
    int base = bbase[blockIdx.x];
    if (i < NN) {
        int o = base + incl - d;
        offsets[i] = o;
        cursor[i]  = o;
        if (i == NN - 1) offsets[NN] = base + incl;
    }
}

__global__ __launch_bounds__(256) void reorder_kernel(
    const int* __restrict__ src, const int* __restrict__ dst,
    int* __restrict__ cursor, int* __restrict__ csr_src)
{
    int e = blockIdx.x * 256 + threadIdx.x;
    if (e < NE) {
        int pos = atomicAdd(&cursor[dst[e]], 1);
        csr_src[pos] = src[e];
    }
}

// -------------------------------------------------------------- aggregate ---
template <bool TRANSFORM>
__global__ __launch_bounds__(256) void aggregate_kernel(
    const float* __restrict__ x, const int* __restrict__ offsets,
    const int* __restrict__ csr_src, const float* __restrict__ sc,
    const float* __restrict__ sh, float* __restrict__ agg)
{
    int tid = blockIdx.x * 256 + threadIdx.x;
    int node = tid >> 5;
    if (node >= NN) return;
    int c4 = (tid & 31) << 2;

    float4 sc4, sh4;
    if (TRANSFORM) {
        sc4 = *reinterpret_cast<const float4*>(sc + c4);
        sh4 = *reinterpret_cast<const float4*>(sh + c4);
    }
    auto xf = [&](float4 v) -> float4 {
        if (TRANSFORM) {
            v.x = fmaxf(fmaf(v.x, sc4.x, sh4.x), 0.f);
            v.y = fmaxf(fmaf(v.y, sc4.y, sh4.y), 0.f);
            v.z = fmaxf(fmaf(v.z, sc4.z, sh4.z), 0.f);
            v.w = fmaxf(fmaf(v.w, sc4.w, sh4.w), 0.f);
        }
        return v;
    };

    int beg = offsets[node], end = offsets[node + 1];
    float4 acc = make_float4(0.f, 0.f, 0.f, 0.f);
    int e = beg;
    for (; e + 3 < end; e += 4) {
        int s0 = csr_src[e], s1 = csr_src[e + 1];
        int s2 = csr_src[e + 2], s3 = csr_src[e + 3];
        float4 v0 = xf(*reinterpret_cast<const float4*>(x + (size_t)s0 * DH + c4));
        float4 v1 = xf(*reinterpret_cast<const float4*>(x + (size_t)s1 * DH + c4));
        float4 v2 = xf(*reinterpret_cast<const float4*>(x + (size_t)s2 * DH + c4));
        float4 v3 = xf(*reinterpret_cast<const float4*>(x + (size_t)s3 * DH + c4));
        acc.x += (v0.x + v1.x) + (v2.x + v3.x);
        acc.y += (v0.y + v1.y) + (v2.y + v3.y);
        acc.z += (v0.z + v1.z) + (v2.z + v3.z);
        acc.w += (v0.w + v1.w) + (v2.w + v3.w);
    }
    for (; e < end; ++e) {
        int s0 = csr_src[e];
        float4 v0 = xf(*reinterpret_cast<const float4*>(x + (size_t)s0 * DH + c4));
        acc.x += v0.x; acc.y += v0.y; acc.z += v0.z; acc.w += v0.w;
    }
    *reinterpret_cast<float4*>(agg + (size_t)node * DH + c4) = acc;
}

// ------------------------------------------------------------------- gemm ---
// OUT = t(X) @ Wr + A @ Wl + bias, t = lazy BN+ReLU (TRANSFORM) or identity.
// 128x128 tile, 256 threads, 8 rows x (4+4 split) cols per thread, K-step 32.
// LDS traffic: 64 B per 64 FMA per thread per kk (1 B/FMA).
template <bool TRANSFORM>
__global__ __launch_bounds__(256, 2) void gemm_fused_kernel(
    const float* __restrict__ X, const float* __restrict__ A,
    const float* __restrict__ Wr, const float* __restrict__ Wl,
    const float* __restrict__ bias, const float* __restrict__ scIn,
    const float* __restrict__ shIn, float* __restrict__ OUT,
    float* __restrict__ stats)
{
    __shared__ float sAT[32][132];      // k-major: [k][row], pad 132
    __shared__ float sW[32][128];
    __shared__ float sScale[DH], sShift[DH];

    const int tid  = threadIdx.x;
    const int c0   = (tid & 15) * 4;     // cols c0..c0+3
    const int c1   = c0 + 64;            // cols c1..c1+3 (split: 2-way LDS, free)
    const int r0   = (tid >> 4) * 8;     // rows r0..r0+7
    const int row0 = blockIdx.x * 128;

    if (TRANSFORM && tid < DH) {
        sScale[tid] = scIn[tid];
        sShift[tid] = shIn[tid];
    }
    __syncthreads();

    float acc[8][8];
#pragma unroll
    for (int r = 0; r < 8; ++r)
#pragma unroll
        for (int j = 0; j < 8; ++j) acc[r][j] = 0.f;

    for (int t = 0; t < 8; ++t) {
        const float* inp = (t < 4) ? X : A;
        const float* Wp  = (t < 4) ? Wr : Wl;
        const int kb = (t * 32) & 127;

        // stage A tile (k-major): 128 rows x 32 k = 1024 float4, 4/thread ----
#pragma unroll
        for (int i = 0; i < 4; ++i) {
            int f = i * 256 + tid;
            int row = f >> 3;              // 0..127
            int kc  = (f & 7) * 4;         // 0..28
            int grow = row0 + row;
            float4 v = make_float4(0.f, 0.f, 0.f, 0.f);
            if (grow < NN) {
                v = *reinterpret_cast<const float4*>(inp + (size_t)grow * DH + kb + kc);
                if (TRANSFORM && t < 4) {
                    int cb = kb + kc;
                    v.x = fmaxf(fmaf(v.x, sScale[cb + 0], sShift[cb + 0]), 0.f);
                    v.y = fmaxf(fmaf(v.y, sScale[cb + 1], sShift[cb + 1]), 0.f);
                    v.z = fmaxf(fmaf(v.z, sScale[cb + 2], sShift[cb + 2]), 0.f);
                    v.w = fmaxf(fmaf(v.w, sScale[cb + 3], sShift[cb + 3]), 0.f);
                }
            }
            sAT[kc + 0][row] = v.x; sAT[kc + 1][row] = v.y;
            sAT[kc + 2][row] = v.z; sAT[kc + 3][row] = v.w;
        }
        // stage W tile: 32 k x 128 cols = 1024 float4, 4/thread -------------
#pragma unroll
        for (int i = 0; i < 4; ++i) {
            int f = i * 256 + tid;
            int kk = f >> 5;
            int cc = (f & 31) * 4;
            *reinterpret_cast<float4*>(&sW[kk][cc]) =
                *reinterpret_cast<const float4*>(Wp + (size_t)(kb + kk) * DH + cc);
        }
        __syncthreads();

        // compute ----------------------------------------------------------
#pragma unroll
        for (int kk = 0; kk < 32; ++kk) {
            float4 a0 = *reinterpret_cast<const float4*>(&sAT[kk][r0]);
            float4 a1 = *reinterpret_cast<const float4*>(&sAT[kk][r0 + 4]);
            float4 w0 = *reinterpret_cast<const float4*>(&sW[kk][c0]);
            float4 w1 = *reinterpret_cast<const float4*>(&sW[kk][c1]);
            float av[8] = {a0.x, a0.y, a0.z, a0.w, a1.x, a1.y, a1.z, a1.w};
            float wv[8] = {w0.x, w0.y, w0.z, w0.w, w1.x, w1.y, w1.z, w1.w};
#pragma unroll
            for (int r = 0; r < 8; ++r)
#pragma unroll
                for (int j = 0; j < 8; ++j)
                    acc[r][j] = fmaf(av[r], wv[j], acc[r][j]);
        }
        __syncthreads();
    }

    // epilogue: bias, store, column stats
    float bv[8];
#pragma unroll
    for (int j = 0; j < 4; ++j) { bv[j] = bias[c0 + j]; bv[4 + j] = bias[c1 + j]; }

    float s_[8] = {0,0,0,0,0,0,0,0}, q_[8] = {0,0,0,0,0,0,0,0};

#pragma unroll
    for (int r = 0; r < 8; ++r) {
        int orow = row0 + r0 + r;
        if (orow < NN) {
            float o[8];
#pragma unroll
            for (int j = 0; j < 8; ++j) {
                o[j] = acc[r][j] + bv[j];
                s_[j] += o[j];
                q_[j] += o[j] * o[j];
            }
            *reinterpret_cast<float4*>(OUT + (size_t)orow * DH + c0) =
                make_float4(o[0], o[1], o[2], o[3]);
            *reinterpret_cast<float4*>(OUT + (size_t)orow * DH + c1) =
                make_float4(o[4], o[5], o[6], o[7]);
        }
    }

    // reduce: lanes l, l+16, l+32, l+48 share columns
#pragma unroll
    for (int j = 0; j < 8; ++j) {
        s_[j] += __shfl_xor(s_[j], 16, 64);
        s_[j] += __shfl_xor(s_[j], 32, 64);
        q_[j] += __shfl_xor(q_[j], 16, 64);
        q_[j] += __shfl_xor(q_[j], 32, 64);
    }
    // reuse dead sAT buffer for the cross-wave reduction
    float* ldsS = &sAT[0][0];            // [4][128]
    float* ldsQ = ldsS + 512;            // [4][128]
    int lane = tid & 63, wave = tid >> 6;
    if (lane < 16) {
#pragma unroll
        for (int j = 0; j < 4; ++j) {
            ldsS[wave * DH + lane * 4 + j]      = s_[j];
            ldsS[wave * DH + 64 + lane * 4 + j] = s_[4 + j];
            ldsQ[wave * DH + lane * 4 + j]      = q_[j];
            ldsQ[wave * DH + 64 + lane * 4 + j] = q_[4 + j];
        }
    }
    __syncthreads();
    if (tid < DH) {
        float s = ldsS[tid] + ldsS[DH + tid] + ldsS[2 * DH + tid] + ldsS[3 * DH + tid];
        float q = ldsQ[tid] + ldsQ[DH + tid] + ldsQ[2 * DH + tid] + ldsQ[3 * DH + tid];
        atomicAdd(&stats[tid], s);
        atomicAdd(&stats[DH + tid], q);
    }
}

// --------------------------------------------------------------- finalize ---
__global__ __launch_bounds__(128) void finalize_kernel(
    const float* __restrict__ stats, const float* __restrict__ gamma,
    const float* __restrict__ beta, float* __restrict__ sc,
    float* __restrict__ sh)
{
    int j = threadIdx.x;
    float mean = stats[j] * (1.f / NN);
    float var  = stats[DH + j] * (1.f / NN) - mean * mean;
    float s = rsqrtf(var + EPSV) * gamma[j];
    sc[j] = s;
    sh[j] = beta[j] - mean * s;
}

// ------------------------------------------------------------------- pool ---
__global__ __launch_bounds__(256) void ghist_kernel(
    const int* __restrict__ batch, int* __restrict__ gdeg)
{
    int n = blockIdx.x * 256 + threadIdx.x;
    if (n < NN) atomicAdd(&gdeg[batch[n]], 1);
}

__global__ __launch_bounds__(1024) void gscan_kernel(
    const int* __restrict__ gdeg, int* __restrict__ goff)
{
    __shared__ int part[1024];
    int t = threadIdx.x;
    part[t] = gdeg[t];
    __syncthreads();
    for (int off = 1; off < 1024; off <<= 1) {
        int v = (t >= off) ? part[t - off] : 0;
        __syncthreads();
        part[t] += v;
        __syncthreads();
    }
    goff[t + 1] = part[t];
    if (t == 0) goff[0] = 0;
}

__global__ __launch_bounds__(128) void pool_seg_kernel(
    const float* __restrict__ H, const int* __restrict__ goff,
    const float* __restrict__ sc, const float* __restrict__ sh,
    float* __restrict__ pooled)
{
    int g = blockIdx.x;
    int j = threadIdx.x;
    int beg = goff[g], end = goff[g + 1];
    float s = 0.f;
    for (int n = beg; n < end; ++n) s += H[(size_t)n * DH + j];
    float cnt = (float)(end - beg);
    float v = s * sc[j] + cnt * sh[j];
    pooled[(size_t)g * DH + j] = v / fmaxf(cnt, 1.f);
}

__global__ __launch_bounds__(64) void classify_kernel(
    const float* __restrict__ pooled, const float* __restrict__ wcls,
    const float* __restrict__ bcls, float* __restrict__ out)
{
    int g = blockIdx.x;
    int lane = threadIdx.x;
    float p0 = pooled[(size_t)g * DH + lane];
    float p1 = pooled[(size_t)g * DH + 64 + lane];
#pragma unroll
    for (int c = 0; c < NC; ++c) {
        float v = p0 * wcls[lane * NC + c] + p1 * wcls[(64 + lane) * NC + c];
#pragma unroll
        for (int off = 32; off > 0; off >>= 1) v += __shfl_down(v, off, 64);
        if (lane == 0) out[(size_t)g * NC + c] = v + bcls[c];
    }
}

// ----------------------------------------------------------------- launch ---
extern "C" void kernel_launch(void* const* d_in, const int* in_sizes, int n_in,
                              void* d_out, int out_size, void* d_ws, size_t ws_size,
                              hipStream_t stream)
{
    const float* x    = (const float*)d_in[0];
    const int*   ei   = (const int*)d_in[1];
    const int*   batch= (const int*)d_in[2];
    const float* wr1  = (const float*)d_in[3];
    const float* wl1  = (const float*)d_in[4];
    const float* b1   = (const float*)d_in[5];
    const float* wr2  = (const float*)d_in[6];
    const float* wl2  = (const float*)d_in[7];
    const float* b2   = (const float*)d_in[8];
    const float* wr3  = (const float*)d_in[9];
    const float* wl3  = (const float*)d_in[10];
    const float* b3   = (const float*)d_in[11];
    const float* g1   = (const float*)d_in[12];
    const float* be1  = (const float*)d_in[13];
    const float* g2   = (const float*)d_in[14];
    const float* be2  = (const float*)d_in[15];
    const float* g3   = (const float*)d_in[16];
    const float* be3  = (const float*)d_in[17];
    const float* wcls = (const float*)d_in[18];
    const float* bcls = (const float*)d_in[19];
    float* out = (float*)d_out;

    const int* srcp = ei;
    const int* dstp = ei + NE;

    char* ws = (char*)d_ws;
    const size_t featB = (size_t)NN * DH * sizeof(float);
    size_t off = 0;
    auto alloc = [&](size_t bytes) {
        void* p = ws + off;
        off += (bytes + 255) & ~(size_t)255;
        return p;
    };
    float* agg     = (float*)alloc(featB);
    float* hA      = (float*)alloc(featB);
    float* hB      = (float*)alloc(featB);
    float* stats   = (float*)alloc(1024);
    float* pooled  = (float*)alloc((size_t)NG * DH * sizeof(float));
    int*   deg     = (int*)alloc(NN * sizeof(int));
    int*   offsets = (int*)alloc((NN + 1) * sizeof(int));
    int*   cursor  = (int*)alloc(NN * sizeof(int));
    int*   csr_src = (int*)alloc(NE * sizeof(int));
    int*   gdeg    = (int*)alloc(NG * sizeof(int));
    int*   goff    = (int*)alloc((NG + 1) * sizeof(int));
    int*   bsum    = (int*)alloc(NB * sizeof(int));
    int*   bbase   = (int*)alloc(NB * sizeof(int));
    float* sc1 = (float*)alloc(DH * 4); float* sh1 = (float*)alloc(DH * 4);
    float* sc2 = (float*)alloc(DH * 4); float* sh2 = (float*)alloc(DH * 4);
    float* sc3 = (float*)alloc(DH * 4); float* sh3 = (float*)alloc(DH * 4);

    const int edgeBlocks = (NE + 255) / 256;
    const int nodeBlocks = (NN + 255) / 256;     // == NB
    const int aggBlocks  = (NN * 32 + 255) / 256;
    const int gemmBlocks = (NN + 127) / 128;     // 391

    // ---- CSR build (once)
    hipMemsetAsync(deg, 0, NN * sizeof(int), stream);
    hist_kernel<<<edgeBlocks, 256, 0, stream>>>(dstp, deg);
    psum_kernel<<<NB, 256, 0, stream>>>(deg, bsum);
    scan_bsums_kernel<<<1, 256, 0, stream>>>(bsum, bbase);
    offsets_kernel<<<NB, 256, 0, stream>>>(deg, bbase, offsets, cursor);
    reorder_kernel<<<edgeBlocks, 256, 0, stream>>>(srcp, dstp, cursor, csr_src);

    // ---- graph ranges for pooling
    hipMemsetAsync(gdeg, 0, NG * sizeof(int), stream);
    ghist_kernel<<<nodeBlocks, 256, 0, stream>>>(batch, gdeg);
    gscan_kernel<<<1, 1024, 0, stream>>>(gdeg, goff);

    // ---- layer 1
    aggregate_kernel<false><<<aggBlocks, 256, 0, stream>>>(x, offsets, csr_src, nullptr, nullptr, agg);
    hipMemsetAsync(stats, 0, 1024, stream);
    gemm_fused_kernel<false><<<gemmBlocks, 256, 0, stream>>>(x, agg, wr1, wl1, b1, nullptr, nullptr, hA, stats);
    finalize_kernel<<<1, 128, 0, stream>>>(stats, g1, be1, sc1, sh1);

    // ---- layer 2
    aggregate_kernel<true><<<aggBlocks, 256, 0, stream>>>(hA, offsets, csr_src, sc1, sh1, agg);
    hipMemsetAsync(stats, 0, 1024, stream);
    gemm_fused_kernel<true><<<gemmBlocks, 256, 0, stream>>>(hA, agg, wr2, wl2, b2, sc1, sh1, hB, stats);
    finalize_kernel<<<1, 128, 0, stream>>>(stats, g2, be2, sc2, sh2);

    // ---- layer 3
    aggregate_kernel<true><<<aggBlocks, 256, 0, stream>>>(hB, offsets, csr_src, sc2, sh2, agg);
    hipMemsetAsync(stats, 0, 1024, stream);
    gemm_fused_kernel<true><<<gemmBlocks, 256, 0, stream>>>(hB, agg, wr3, wl3, b3, sc2, sh2, hA, stats);
    finalize_kernel<<<1, 128, 0, stream>>>(stats, g3, be3, sc3, sh3);

    // ---- pool (applies BN3, no ReLU) + classify
    pool_seg_kernel<<<NG, 128, 0, stream>>>(hA, goff, sc3, sh3, pooled);
    classify_kernel<<<NG, 64, 0, stream>>>(pooled, wcls, bcls, out);
}